// Round 1
// baseline (417.619 us; speedup 1.0000x reference)
//
#include <hip/hip_runtime.h>

// Problem constants (fixed by the reference's setup_inputs).
#define BATCH 8
#define CH    16
#define HH    512
#define WW    512
#define HW    (HH * WW)     // 262144

#define TILE  32            // output tile edge per block
#define RPAD  16            // halo radius staged in LDS
#define REG   64            // staged region edge = TILE + 2*RPAD
#define NPX   4             // pixels per thread = TILE*TILE / 256
#define CG    2             // channels per group (float2 channel-last in LDS)
#define NG    (CH / CG)     // 8 groups

// One block = one (b, 32x32 tile). Channel-last LDS: sreg[y*REG+x] holds the
// float2 of 2 consecutive channels at (y,x). LDS is 32 KB/block (was 64 KB
// with CG=4): 5 blocks/CU resident instead of 2 -> ~60% occupancy ceiling,
// which is the lever this revision pulls (previous version was latency-bound
// at 20% occupancy, every pipe <25% busy).
// Staging: 2 coalesced global loads + 1 conflict-free ds_write_b64 per
// 64-wide row slice. Gather: 4 ds_read_b64 per pixel per group.
// LDS gather addresses are CLAMPED into the region (branchless); pixels whose
// corners fall outside the staged halo get finite garbage, then are
// overwritten by a per-pixel global-gather fixup loop afterwards (same thread
// stores both -> program order guarantees the final value). The fixup path
// recomputes weights/indices from a flow reload so the main loop carries less
// per-thread state (VGPR slimming: w[16] + lidx[4] + dxv[4] + dyov[4] + 1
// bitmask instead of the previous 9 arrays).
// Validity per reference: tested on UNCLIPPED floor coords; the 0/1 mask is
// folded into the weights (bit-exact); clamped image indices are always
// in-bounds so fixup loads are unconditional.
// blockIdx is XCD-swizzled (bijective: 2048 % 8 == 0) so each XCD owns one
// contiguous batch -> neighboring tiles' halos hit the same XCD L2.
__global__ __launch_bounds__(256) void warp_c2(
    const float* __restrict__ img,
    const float* __restrict__ flo,
    float* __restrict__ out)
{
    __shared__ float2 sreg[REG * REG];   // 32 KB

    const int t   = threadIdx.x;
    const int bid = blockIdx.x;           // 0..2047
    const int tile = (bid & 7) * 256 + (bid >> 3);   // XCD-contiguous chunks
    const int b    = tile >> 8;
    const int ty   = (tile >> 4) & 15;
    const int tx   = tile & 15;
    const int xb   = tx * TILE;
    const int yb   = ty * TILE;
    const int x0r  = xb - RPAD;           // region origin (may be negative)
    const int y0r  = yb - RPAD;

    // ---- per-pixel precompute (channel-invariant) ----
    float w00[NPX], w01[NPX], w10[NPX], w11[NPX];
    int   lidx[NPX], dxv[NPX], dyov[NPX];
    int   fbmask = 0;

    const float* fbp = flo + (size_t)b * 2 * HW;

#pragma unroll
    for (int p = 0; p < NPX; ++p) {
        const int pix = p * 256 + t;      // 0..1023 within tile
        const int row = pix >> 5;
        const int col = pix & 31;
        const int h   = yb + row;
        const int w   = xb + col;
        const int hw  = h * WW + w;

        const float fx = fbp[hw];         // coalesced
        const float fy = fbp[HW + hw];
        const float gx = (float)w + fx;
        const float gy = (float)h + fy;

        const float x0f = floorf(gx), y0f = floorf(gy);
        const float wx1 = gx - x0f, wx0 = 1.0f - wx1;
        const float wy1 = gy - y0f, wy0 = 1.0f - wy1;

        const bool vx0 = (x0f >= 0.0f)        && (x0f <= (float)(WW - 1));
        const bool vx1 = (x0f + 1.0f >= 0.0f) && (x0f + 1.0f <= (float)(WW - 1));
        const bool vy0 = (y0f >= 0.0f)        && (y0f <= (float)(HH - 1));
        const bool vy1 = (y0f + 1.0f >= 0.0f) && (y0f + 1.0f <= (float)(HH - 1));

        float a00 = wx0 * wy0 * ((vx0 && vy0) ? 1.0f : 0.0f);
        float a01 = wx1 * wy0 * ((vx1 && vy0) ? 1.0f : 0.0f);
        float a10 = wx0 * wy1 * ((vx0 && vy1) ? 1.0f : 0.0f);
        float a11 = wx1 * wy1 * ((vx1 && vy1) ? 1.0f : 0.0f);

        const float msum = a00 + a01 + a10 + a11;
        const float mask = (msum < 0.9999f) ? 0.0f : 1.0f;
        w00[p] = a00 * mask; w01[p] = a01 * mask;
        w10[p] = a10 * mask; w11[p] = a11 * mask;

        const int x0 = min(max((int)x0f, 0), WW - 1);
        const int x1 = min(max((int)x0f + 1, 0), WW - 1);
        const int y0 = min(max((int)y0f, 0), HH - 1);
        const int y1 = min(max((int)y0f + 1, 0), HH - 1);

        const int dx = x1 - x0;           // 0 or 1
        const int dy = y1 - y0;
        dxv[p]  = dx;
        dyov[p] = dy * REG;

        const int xl = x0 - x0r;          // region-local (may be out of range)
        const int yl = y0 - y0r;
        if (!((xl >= 0) && (xl + dx <= REG - 1) &&
              (yl >= 0) && (yl + dy <= REG - 1)))
            fbmask |= (1 << p);
        // Clamp to [0, REG-2]: exact for every in-region pixel (an in-region
        // corner with xl==REG-1 implies dx==0 is impossible here -- proven by
        // tile geometry), safe-finite for fallback pixels.
        lidx[p] = min(max(yl, 0), REG - 2) * REG + min(max(xl, 0), REG - 2);
    }

    // ---- staging geometry (channel-invariant) ----
    const int lane = t & 63;
    const int wv   = t >> 6;
    const int gxc  = min(max(x0r + lane, 0), WW - 1);
    const size_t ib = (size_t)b * CH * HW;

    for (int g = 0; g < NG; ++g) {
        const float* c0 = img + ib + (size_t)(g * CG) * HW;

        // stage 64x64 region, 2 channels deep (channel-last float2)
#pragma unroll
        for (int k = 0; k < 16; ++k) {
            const int ry = k * 4 + wv;                       // 0..63
            const int gy = min(max(y0r + ry, 0), HH - 1);
            const int go = gy * WW + gxc;
            float2 v;
            v.x = c0[go];
            v.y = c0[go + HW];
            sreg[ry * REG + lane] = v;    // ds_write_b64, conflict-free
        }
        __syncthreads();

        float* o0 = out + ib + (size_t)(g * CG) * HW;
#pragma unroll
        for (int p = 0; p < NPX; ++p) {
            const int l   = lidx[p];
            const int dx  = dxv[p];
            const int dyo = dyov[p];
            const float2 v00 = sreg[l];
            const float2 v01 = sreg[l + dx];
            const float2 v10 = sreg[l + dyo];
            const float2 v11 = sreg[l + dx + dyo];
            float2 r;
            r.x = w00[p]*v00.x + w01[p]*v01.x + w10[p]*v10.x + w11[p]*v11.x;
            r.y = w00[p]*v00.y + w01[p]*v01.y + w10[p]*v10.y + w11[p]*v11.y;
            const int pix = p * 256 + t;
            const int ob  = (yb + (pix >> 5)) * WW + xb + (pix & 31);
            o0[ob]      = r.x;            // coalesced per channel
            o0[ob + HW] = r.y;
        }
        __syncthreads();                  // protect sreg before next group
    }

    // ---- fixup: redo fallback pixels from global (all 16 channels) ----
    // Rare path (~a few % of pixels). Recomputes weights/indices from a flow
    // reload (L2-hot) so the main loop doesn't carry g00/obase/fb arrays.
    if (fbmask) {
#pragma unroll
        for (int p = 0; p < NPX; ++p) {
            if (!(fbmask & (1 << p))) continue;
            const int pix = p * 256 + t;
            const int row = pix >> 5;
            const int col = pix & 31;
            const int h   = yb + row;
            const int w   = xb + col;
            const int hw  = h * WW + w;

            const float fx = fbp[hw];
            const float fy = fbp[HW + hw];
            const float gx = (float)w + fx;
            const float gy = (float)h + fy;

            const float x0f = floorf(gx), y0f = floorf(gy);
            const float wx1 = gx - x0f, wx0 = 1.0f - wx1;
            const float wy1 = gy - y0f, wy0 = 1.0f - wy1;

            const bool vx0 = (x0f >= 0.0f)        && (x0f <= (float)(WW - 1));
            const bool vx1 = (x0f + 1.0f >= 0.0f) && (x0f + 1.0f <= (float)(WW - 1));
            const bool vy0 = (y0f >= 0.0f)        && (y0f <= (float)(HH - 1));
            const bool vy1 = (y0f + 1.0f >= 0.0f) && (y0f + 1.0f <= (float)(HH - 1));

            float a00 = wx0 * wy0 * ((vx0 && vy0) ? 1.0f : 0.0f);
            float a01 = wx1 * wy0 * ((vx1 && vy0) ? 1.0f : 0.0f);
            float a10 = wx0 * wy1 * ((vx0 && vy1) ? 1.0f : 0.0f);
            float a11 = wx1 * wy1 * ((vx1 && vy1) ? 1.0f : 0.0f);

            const float msum = a00 + a01 + a10 + a11;
            const float mask = (msum < 0.9999f) ? 0.0f : 1.0f;
            a00 *= mask; a01 *= mask; a10 *= mask; a11 *= mask;

            const int x0 = min(max((int)x0f, 0), WW - 1);
            const int x1 = min(max((int)x0f + 1, 0), WW - 1);
            const int y0 = min(max((int)y0f, 0), HH - 1);
            const int y1 = min(max((int)y0f + 1, 0), HH - 1);

            const int gA  = y0 * WW + x0;
            const int dx  = x1 - x0;
            const int dyo = (y1 - y0) * WW;

            const float* ic = img + ib;
            float*       oc = out + ib + hw;
            for (int c = 0; c < CH; ++c) {
                const float* pc = ic + (size_t)c * HW;
                const float v = a00 * pc[gA]
                              + a01 * pc[gA + dx]
                              + a10 * pc[gA + dyo]
                              + a11 * pc[gA + dx + dyo];
                oc[(size_t)c * HW] = v;
            }
        }
    }
}

extern "C" void kernel_launch(void* const* d_in, const int* in_sizes, int n_in,
                              void* d_out, int out_size, void* d_ws, size_t ws_size,
                              hipStream_t stream) {
    const float* img = (const float*)d_in[0];  // [8,16,512,512] fp32
    const float* flo = (const float*)d_in[1];  // [8,2,512,512] fp32
    float* out = (float*)d_out;                // [8,16,512,512] fp32

    const int blocks = BATCH * (HH / TILE) * (WW / TILE);  // 2048
    warp_c2<<<blocks, 256, 0, stream>>>(img, flo, out);
}

// Round 2
// 293.346 us; speedup vs baseline: 1.4236x; 1.4236x over previous
//
#include <hip/hip_runtime.h>

// Problem constants (fixed by the reference's setup_inputs).
#define BATCH 8
#define CH    16
#define HH    512
#define WW    512
#define HW    (HH * WW)     // 262144

#define TILE  32            // output tile edge per block
#define RPAD  16            // halo radius staged in LDS
#define REG   64            // staged region edge = TILE + 2*RPAD
#define NPX   4             // pixels per thread = TILE*TILE / 256
#define CG    4             // channels per group (float4 channel-last in LDS)
#define NG    (CH / CG)     // 4 groups

// One block = one (b, 32x32 tile). Channel-last LDS: sreg[y*REG+x] holds the
// float4 of 4 consecutive channels at (y,x).
//
// R2 change: register ping-pong prefetch (T14 async-STAGE split). Round 0/1
// showed the kernel is ~90% stalled: every staging phase was
// issue-loads -> vmcnt(0) -> ds_write -> barrier with nothing hiding the
// HBM/L2 latency, and raising occupancy (R1, CG=2) made it WORSE because it
// doubled the number of these serialized phases. Here group g+1's staging
// loads are issued into registers (pB/pA) BEFORE the gather of group g, so
// the vmcnt drain at the phase-end barrier lands after ~the whole gather
// phase has covered the load latency. This costs ~128 VGPRs, which is FREE:
// 64 KB LDS pins residency at 2 blocks/CU = 2 waves/SIMD, and 2 waves/SIMD
// tolerates up to 256 VGPRs (__launch_bounds__(256,2) pins that). Group 0's
// load latency is hidden under the per-pixel flow precompute.
//
// Kept from R1: XCD-contiguous blockIdx swizzle (bijective, 2048%8==0) --
// FETCH_SIZE dropped 229MB -> 104MB per dispatch (cross-tile halo reuse now
// hits the same XCD's L2). Kept: fbmask + fixup-recompute (register slim).
//
// Validity per reference: tested on UNCLIPPED floor coords; the 0/1 mask is
// folded into the weights (bit-exact); clamped image indices are always
// in-bounds so fixup loads are unconditional. LDS gather addresses are
// CLAMPED into the region (branchless); pixels whose corners fall outside
// the staged halo get finite garbage, then are overwritten by the per-pixel
// global-gather fixup loop (same thread stores both -> program order).

#define LOADG(g, pr) do {                                               \
    const float* c0_ = img + ib + (size_t)((g) * CG) * HW;              \
    _Pragma("unroll")                                                   \
    for (int k = 0; k < 16; ++k) {                                      \
        const int go_ = goff[k];                                        \
        pr[k].x = c0_[go_];                                             \
        pr[k].y = c0_[go_ + HW];                                        \
        pr[k].z = c0_[go_ + 2 * HW];                                    \
        pr[k].w = c0_[go_ + 3 * HW];                                    \
    }                                                                   \
} while (0)

#define WRITELDS(pr) do {                                               \
    _Pragma("unroll")                                                   \
    for (int k = 0; k < 16; ++k)                                        \
        sreg[(k * 4 + wv) * REG + lane] = pr[k];                        \
} while (0)

#define GATHER(g) do {                                                  \
    float* o0_ = out + ib + (size_t)((g) * CG) * HW;                    \
    _Pragma("unroll")                                                   \
    for (int p = 0; p < NPX; ++p) {                                     \
        const int l_   = lidx[p];                                       \
        const int dx_  = dxv[p];                                        \
        const int dyo_ = dyov[p];                                       \
        const float4 v00 = sreg[l_];                                    \
        const float4 v01 = sreg[l_ + dx_];                              \
        const float4 v10 = sreg[l_ + dyo_];                             \
        const float4 v11 = sreg[l_ + dx_ + dyo_];                       \
        float4 r_;                                                      \
        r_.x = w00[p]*v00.x + w01[p]*v01.x + w10[p]*v10.x + w11[p]*v11.x; \
        r_.y = w00[p]*v00.y + w01[p]*v01.y + w10[p]*v10.y + w11[p]*v11.y; \
        r_.z = w00[p]*v00.z + w01[p]*v01.z + w10[p]*v10.z + w11[p]*v11.z; \
        r_.w = w00[p]*v00.w + w01[p]*v01.w + w10[p]*v10.w + w11[p]*v11.w; \
        const int pix_ = p * 256 + t;                                   \
        const int ob_  = (yb + (pix_ >> 5)) * WW + xb + (pix_ & 31);    \
        o0_[ob_]          = r_.x;                                       \
        o0_[ob_ + HW]     = r_.y;                                       \
        o0_[ob_ + 2*HW]   = r_.z;                                       \
        o0_[ob_ + 3*HW]   = r_.w;                                       \
    }                                                                   \
} while (0)

__global__ __launch_bounds__(256, 2) void warp_pf(
    const float* __restrict__ img,
    const float* __restrict__ flo,
    float* __restrict__ out)
{
    __shared__ float4 sreg[REG * REG];   // 64 KB -> 2 blocks/CU

    const int t   = threadIdx.x;
    const int bid = blockIdx.x;           // 0..2047
    const int tile = (bid & 7) * 256 + (bid >> 3);   // XCD-contiguous chunks
    const int b    = tile >> 8;
    const int ty   = (tile >> 4) & 15;
    const int tx   = tile & 15;
    const int xb   = tx * TILE;
    const int yb   = ty * TILE;
    const int x0r  = xb - RPAD;           // region origin (may be negative)
    const int y0r  = yb - RPAD;

    // ---- staging geometry (channel-invariant) ----
    const int lane = t & 63;
    const int wv   = t >> 6;
    const int gxc  = min(max(x0r + lane, 0), WW - 1);
    const size_t ib = (size_t)b * CH * HW;

    int goff[16];                         // per-thread staged-row offsets
#pragma unroll
    for (int k = 0; k < 16; ++k) {
        const int ry = k * 4 + wv;        // 0..63
        const int gy = min(max(y0r + ry, 0), HH - 1);
        goff[k] = gy * WW + gxc;
    }

    // ---- issue group-0 staging loads; precompute hides their latency ----
    float4 pA[16], pB[16];
    LOADG(0, pA);

    // ---- per-pixel precompute (channel-invariant) ----
    float w00[NPX], w01[NPX], w10[NPX], w11[NPX];
    int   lidx[NPX], dxv[NPX], dyov[NPX];
    int   fbmask = 0;

    const float* fbp = flo + (size_t)b * 2 * HW;

#pragma unroll
    for (int p = 0; p < NPX; ++p) {
        const int pix = p * 256 + t;      // 0..1023 within tile
        const int row = pix >> 5;
        const int col = pix & 31;
        const int h   = yb + row;
        const int w   = xb + col;
        const int hw  = h * WW + w;

        const float fx = fbp[hw];         // coalesced
        const float fy = fbp[HW + hw];
        const float gx = (float)w + fx;
        const float gy = (float)h + fy;

        const float x0f = floorf(gx), y0f = floorf(gy);
        const float wx1 = gx - x0f, wx0 = 1.0f - wx1;
        const float wy1 = gy - y0f, wy0 = 1.0f - wy1;

        const bool vx0 = (x0f >= 0.0f)        && (x0f <= (float)(WW - 1));
        const bool vx1 = (x0f + 1.0f >= 0.0f) && (x0f + 1.0f <= (float)(WW - 1));
        const bool vy0 = (y0f >= 0.0f)        && (y0f <= (float)(HH - 1));
        const bool vy1 = (y0f + 1.0f >= 0.0f) && (y0f + 1.0f <= (float)(HH - 1));

        float a00 = wx0 * wy0 * ((vx0 && vy0) ? 1.0f : 0.0f);
        float a01 = wx1 * wy0 * ((vx1 && vy0) ? 1.0f : 0.0f);
        float a10 = wx0 * wy1 * ((vx0 && vy1) ? 1.0f : 0.0f);
        float a11 = wx1 * wy1 * ((vx1 && vy1) ? 1.0f : 0.0f);

        const float msum = a00 + a01 + a10 + a11;
        const float mask = (msum < 0.9999f) ? 0.0f : 1.0f;
        w00[p] = a00 * mask; w01[p] = a01 * mask;
        w10[p] = a10 * mask; w11[p] = a11 * mask;

        const int x0 = min(max((int)x0f, 0), WW - 1);
        const int x1 = min(max((int)x0f + 1, 0), WW - 1);
        const int y0 = min(max((int)y0f, 0), HH - 1);
        const int y1 = min(max((int)y0f + 1, 0), HH - 1);

        const int dx = x1 - x0;           // 0 or 1
        const int dy = y1 - y0;
        dxv[p]  = dx;
        dyov[p] = dy * REG;

        const int xl = x0 - x0r;          // region-local (may be out of range)
        const int yl = y0 - y0r;
        if (!((xl >= 0) && (xl + dx <= REG - 1) &&
              (yl >= 0) && (yl + dy <= REG - 1)))
            fbmask |= (1 << p);
        // Clamp to [0, REG-2]: exact for every in-region pixel, safe-finite
        // for fallback pixels (overwritten by fixup).
        lidx[p] = min(max(yl, 0), REG - 2) * REG + min(max(xl, 0), REG - 2);
    }

    // ---- main loop, fully unrolled, register ping-pong prefetch ----
    // g = 0
    WRITELDS(pA);                // waits on pA loads only
    __syncthreads();
    LOADG(1, pB);                // in flight across the whole gather of g=0
    GATHER(0);
    __syncthreads();             // drains pB loads AFTER gather covered them
    // g = 1
    WRITELDS(pB);
    __syncthreads();
    LOADG(2, pA);
    GATHER(1);
    __syncthreads();
    // g = 2
    WRITELDS(pA);
    __syncthreads();
    LOADG(3, pB);
    GATHER(2);
    __syncthreads();
    // g = 3
    WRITELDS(pB);
    __syncthreads();
    GATHER(3);

    // ---- fixup: redo fallback pixels from global (all 16 channels) ----
    // Rare path. Recomputes weights/indices from a flow reload (L2-hot).
    if (fbmask) {
#pragma unroll
        for (int p = 0; p < NPX; ++p) {
            if (!(fbmask & (1 << p))) continue;
            const int pix = p * 256 + t;
            const int row = pix >> 5;
            const int col = pix & 31;
            const int h   = yb + row;
            const int w   = xb + col;
            const int hw  = h * WW + w;

            const float fx = fbp[hw];
            const float fy = fbp[HW + hw];
            const float gx = (float)w + fx;
            const float gy = (float)h + fy;

            const float x0f = floorf(gx), y0f = floorf(gy);
            const float wx1 = gx - x0f, wx0 = 1.0f - wx1;
            const float wy1 = gy - y0f, wy0 = 1.0f - wy1;

            const bool vx0 = (x0f >= 0.0f)        && (x0f <= (float)(WW - 1));
            const bool vx1 = (x0f + 1.0f >= 0.0f) && (x0f + 1.0f <= (float)(WW - 1));
            const bool vy0 = (y0f >= 0.0f)        && (y0f <= (float)(HH - 1));
            const bool vy1 = (y0f + 1.0f >= 0.0f) && (y0f + 1.0f <= (float)(HH - 1));

            float a00 = wx0 * wy0 * ((vx0 && vy0) ? 1.0f : 0.0f);
            float a01 = wx1 * wy0 * ((vx1 && vy0) ? 1.0f : 0.0f);
            float a10 = wx0 * wy1 * ((vx0 && vy1) ? 1.0f : 0.0f);
            float a11 = wx1 * wy1 * ((vx1 && vy1) ? 1.0f : 0.0f);

            const float msum = a00 + a01 + a10 + a11;
            const float mask = (msum < 0.9999f) ? 0.0f : 1.0f;
            a00 *= mask; a01 *= mask; a10 *= mask; a11 *= mask;

            const int x0 = min(max((int)x0f, 0), WW - 1);
            const int x1 = min(max((int)x0f + 1, 0), WW - 1);
            const int y0 = min(max((int)y0f, 0), HH - 1);
            const int y1 = min(max((int)y0f + 1, 0), HH - 1);

            const int gA  = y0 * WW + x0;
            const int dx  = x1 - x0;
            const int dyo = (y1 - y0) * WW;

            const float* ic = img + ib;
            float*       oc = out + ib + hw;
            for (int c = 0; c < CH; ++c) {
                const float* pc = ic + (size_t)c * HW;
                const float v = a00 * pc[gA]
                              + a01 * pc[gA + dx]
                              + a10 * pc[gA + dyo]
                              + a11 * pc[gA + dx + dyo];
                oc[(size_t)c * HW] = v;
            }
        }
    }
}

extern "C" void kernel_launch(void* const* d_in, const int* in_sizes, int n_in,
                              void* d_out, int out_size, void* d_ws, size_t ws_size,
                              hipStream_t stream) {
    const float* img = (const float*)d_in[0];  // [8,16,512,512] fp32
    const float* flo = (const float*)d_in[1];  // [8,2,512,512] fp32
    float* out = (float*)d_out;                // [8,16,512,512] fp32

    const int blocks = BATCH * (HH / TILE) * (WW / TILE);  // 2048
    warp_pf<<<blocks, 256, 0, stream>>>(img, flo, out);
}